// Round 4
// baseline (760.779 us; speedup 1.0000x reference)
//
#include <hip/hip_runtime.h>

#define NODES 50000
#define NEDGE 800000
#define FDIM  128

typedef __bf16 bf16x8 __attribute__((ext_vector_type(8)));
typedef float  f32x4  __attribute__((ext_vector_type(4)));

// Band coefficients B[i][k] = A[i][k] - A[i+1][k] (i=0..2), B[3] = A[3] (verified round 1).
__device__ __constant__ float BCOEF[4][9] = {
  { 0.35496460f,  0.31284160f, -0.03870412f,  0.00320868f, -1.99927e-4f,
    9.97480e-6f, -4.15015e-7f,  1.48054e-8f, -4.62272e-10f },
  { 0.27760180f,  0.12523720f, -0.11205788f,  0.03283760f, -0.00637710f,
    9.58661e-4f, -1.19074e-4f,  1.26613e-5f, -1.17878e-6f },
  { 0.16043170f, -0.08057710f, -0.08449120f,  0.08620240f, -0.04530300f,
    0.01752000f, -0.00553870f,  0.00150130f, -3.58171e-4f },
  { 0.20700190f, -0.35750170f,  0.23525320f, -0.12224870f,  0.05188000f,
   -0.01848860f,  0.00565820f, -0.00151400f,  3.59350e-4f }
};

__global__ void hist_kernel(const int* __restrict__ row, int* __restrict__ cnt, int e) {
    int i = blockIdx.x * blockDim.x + threadIdx.x;
    if (i < e) atomicAdd(&cnt[row[i]], 1);
}

__global__ void scan_kernel(const int* __restrict__ cnt, int* __restrict__ rowptr, int n) {
    __shared__ int buf[1024];
    __shared__ int carry;
    int tid = threadIdx.x;
    if (tid == 0) carry = 0;
    for (int base = 0; base < n; base += 1024) {
        int i = base + tid;
        int v = (i < n) ? cnt[i] : 0;
        __syncthreads();
        buf[tid] = v;
        __syncthreads();
        for (int off = 1; off < 1024; off <<= 1) {
            int t = (tid >= off) ? buf[tid - off] : 0;
            __syncthreads();
            buf[tid] += t;
            __syncthreads();
        }
        int incl = buf[tid];
        int c = carry;
        if (i < n) rowptr[i] = c + incl - v;
        __syncthreads();
        if (tid == 1023) carry = c + incl;
    }
    __syncthreads();
    if (tid == 0) rowptr[n] = carry;
}

__global__ void scatter_kernel(const int* __restrict__ row, const int* __restrict__ col,
                               const float* __restrict__ w, int* __restrict__ cursor,
                               int* __restrict__ ccol, float* __restrict__ cw, int e) {
    int i = blockIdx.x * blockDim.x + threadIdx.x;
    if (i < e) {
        int r = row[i];
        int pos = atomicAdd(&cursor[r], 1);
        ccol[pos] = col[i];
        cw[pos]  = w[i];
    }
}

// wave-per-row SpMM: lane holds features (2*lane, 2*lane+1); edge loop unrolled x4
// for 4 outstanding gathers (was 1 -> latency-bound at ~160us/dispatch).
__global__ __launch_bounds__(256) void spmm2(
    const int* __restrict__ rowptr, const int* __restrict__ cols,
    const float* __restrict__ wts, const float* __restrict__ pin,
    const float* __restrict__ psub, float* __restrict__ pout,
    float alpha, int n)
{
    int row = blockIdx.x * 4 + (threadIdx.x >> 6);
    if (row >= n) return;
    int lane = threadIdx.x & 63;
    int s = rowptr[row], e = rowptr[row + 1];
    const float2* pin2 = reinterpret_cast<const float2*>(pin);
    float ax0 = 0.f, ay0 = 0.f, ax1 = 0.f, ay1 = 0.f;
    float ax2 = 0.f, ay2 = 0.f, ax3 = 0.f, ay3 = 0.f;
    int i = s;
    for (; i + 4 <= e; i += 4) {
        int c0 = cols[i], c1 = cols[i + 1], c2 = cols[i + 2], c3 = cols[i + 3];
        float w0 = wts[i], w1 = wts[i + 1], w2 = wts[i + 2], w3 = wts[i + 3];
        float2 v0 = pin2[(size_t)c0 * 64 + lane];
        float2 v1 = pin2[(size_t)c1 * 64 + lane];
        float2 v2 = pin2[(size_t)c2 * 64 + lane];
        float2 v3 = pin2[(size_t)c3 * 64 + lane];
        ax0 += w0 * v0.x; ay0 += w0 * v0.y;
        ax1 += w1 * v1.x; ay1 += w1 * v1.y;
        ax2 += w2 * v2.x; ay2 += w2 * v2.y;
        ax3 += w3 * v3.x; ay3 += w3 * v3.y;
    }
    for (; i < e; ++i) {
        int c = cols[i]; float wv = wts[i];
        float2 v = pin2[(size_t)c * 64 + lane];
        ax0 += wv * v.x; ay0 += wv * v.y;
    }
    float rx = alpha * ((ax0 + ax1) + (ax2 + ax3));
    float ry = alpha * ((ay0 + ay1) + (ay2 + ay3));
    size_t off = (size_t)row * 64 + lane;
    if (psub) {
        float2 sv = reinterpret_cast<const float2*>(psub)[off];
        rx -= sv.x; ry -= sv.y;
    }
    reinterpret_cast<float2*>(pout)[off] = make_float2(rx, ry);
}

// ---------------- MFMA epilogue ----------------
// LDS map (16B chunks): slots 0..3 = bands_i -> H_i [32][128] bf16, slot 4 = X bf16,
// then Wt (transposed weights) [128 o][128 k] bf16. XOR swizzle c ^= (row&15) makes
// all ds_read_b128 fragment reads <=2-way bank aliased (free per m136).
#define RIDX(s, r, c) ((((s) << 9) + ((r) << 4) + ((c) ^ ((r) & 15))) << 3)
#define WIDX(o, c)    (((2560 + ((o) << 4) + ((c) ^ ((o) & 15)))) << 3)

__device__ __forceinline__ void stage_wt(const float* __restrict__ Wsrc, __bf16* SW) {
    // Wsrc: [128 k][128 o] f32 row-major -> LDS Wt[o][k] bf16 (swizzled)
    for (int it = 0; it < 8; ++it) {
        int task = it * 256 + threadIdx.x;   // 0..2047
        int o = task & 127, c = task >> 7;   // chunk c covers k = c*8..c*8+7
        const float* colp = Wsrc + (size_t)(c * 8) * 128 + o;
        bf16x8 v;
#pragma unroll
        for (int j = 0; j < 8; ++j) v[j] = (__bf16)colp[(size_t)j * 128];
        *reinterpret_cast<bf16x8*>(&SW[WIDX(o, c)]) = v;
    }
}

__global__ __launch_bounds__(256) void epilogue_kernel(
    const float* __restrict__ X,        // [N][128]
    const float* __restrict__ psi,      // [8][N][128]
    const float* __restrict__ W_band,   // [4][128][128]
    const float* __restrict__ b_band,   // [4][128]
    const float* __restrict__ W_fuse,   // [640][128]
    const float* __restrict__ b_fuse,   // [128]
    float* __restrict__ out)            // [N][128]
{
    __shared__ __align__(16) __bf16 SW[36864];   // 72 KB -> 2 blocks/CU
    const int tid = threadIdx.x;
    const int n0 = blockIdx.x * 32;

    // Phase 1: bands (f32 combine of 9 Psi arrays) -> bf16 LDS; X -> bf16 LDS slot 4.
    for (int t = tid; t < 512; t += 256) {
        int row = t >> 4, c = t & 15;
        int node = n0 + row;
        bool ok = node < NODES;
        float bacc[4][8];
#pragma unroll
        for (int i = 0; i < 4; ++i)
#pragma unroll
            for (int j = 0; j < 8; ++j) bacc[i][j] = 0.f;
#pragma unroll
        for (int k = 0; k <= 8; ++k) {
            const float* src = (k == 0)
                ? X + (size_t)node * FDIM + c * 8
                : psi + ((size_t)(k - 1) * NODES + node) * FDIM + c * 8;
            float4 q0 = make_float4(0.f, 0.f, 0.f, 0.f), q1 = q0;
            if (ok) {
                q0 = reinterpret_cast<const float4*>(src)[0];
                q1 = reinterpret_cast<const float4*>(src)[1];
            }
            float pk[8] = {q0.x, q0.y, q0.z, q0.w, q1.x, q1.y, q1.z, q1.w};
            if (k == 0) {
                bf16x8 xv;
#pragma unroll
                for (int j = 0; j < 8; ++j) xv[j] = (__bf16)pk[j];
                *reinterpret_cast<bf16x8*>(&SW[RIDX(4, row, c)]) = xv;
            }
#pragma unroll
            for (int i = 0; i < 4; ++i)
#pragma unroll
                for (int j = 0; j < 8; ++j) bacc[i][j] += BCOEF[i][k] * pk[j];
        }
#pragma unroll
        for (int i = 0; i < 4; ++i) {
            bf16x8 bv;
#pragma unroll
            for (int j = 0; j < 8; ++j) bv[j] = (__bf16)bacc[i][j];
            *reinterpret_cast<bf16x8*>(&SW[RIDX(i, row, c)]) = bv;
        }
    }

    const int l  = tid & 63, w = tid >> 6;
    const int lo = l & 15, hi = l >> 4;
    const int m  = w & 1, nb = (w >> 1) * 4;   // wave -> (M-tile, 4 N-tiles)

    // Phase 2: per-band GEMM H_i = relu(bands_i @ W_i + b_i), H_i overwrites bands_i.
    for (int i = 0; i < 4; ++i) {
        __syncthreads();                       // R_i ready / prev Wt reads done
        stage_wt(W_band + (size_t)i * 128 * 128, SW);
        __syncthreads();
        f32x4 hacc[4];
#pragma unroll
        for (int n = 0; n < 4; ++n) hacc[n] = (f32x4){0.f, 0.f, 0.f, 0.f};
#pragma unroll
        for (int k = 0; k < 4; ++k) {
            bf16x8 a = *reinterpret_cast<const bf16x8*>(&SW[RIDX(i, m * 16 + lo, k * 4 + hi)]);
#pragma unroll
            for (int n = 0; n < 4; ++n) {
                bf16x8 b = *reinterpret_cast<const bf16x8*>(&SW[WIDX((nb + n) * 16 + lo, k * 4 + hi)]);
                hacc[n] = __builtin_amdgcn_mfma_f32_16x16x32_bf16(a, b, hacc[n], 0, 0, 0);
            }
        }
        __syncthreads();                       // all reads of R_i done before overwrite
#pragma unroll
        for (int n = 0; n < 4; ++n) {
            float bb = b_band[i * 128 + (nb + n) * 16 + lo];
#pragma unroll
            for (int r = 0; r < 4; ++r) {
                float h = hacc[n][r] + bb;
                h = h > 0.f ? h : 0.f;
                int row = m * 16 + hi * 4 + r;
                int o   = (nb + n) * 16 + lo;
                SW[((i << 9) + (row << 4) + (((o >> 3)) ^ (row & 15))) * 8 + (o & 7)] = (__bf16)h;
            }
        }
    }

    // Phase 3: fuse GEMM over K=640 = slots {H0,H1,H2,H3,X} x 128.
    f32x4 facc[4];
#pragma unroll
    for (int n = 0; n < 4; ++n) facc[n] = (f32x4){0.f, 0.f, 0.f, 0.f};
    for (int kc = 0; kc < 5; ++kc) {
        __syncthreads();                       // prev Wt reads / H writes done
        stage_wt(W_fuse + (size_t)kc * 128 * 128, SW);
        __syncthreads();
#pragma unroll
        for (int k = 0; k < 4; ++k) {
            bf16x8 a = *reinterpret_cast<const bf16x8*>(&SW[RIDX(kc, m * 16 + lo, k * 4 + hi)]);
#pragma unroll
            for (int n = 0; n < 4; ++n) {
                bf16x8 b = *reinterpret_cast<const bf16x8*>(&SW[WIDX((nb + n) * 16 + lo, k * 4 + hi)]);
                facc[n] = __builtin_amdgcn_mfma_f32_16x16x32_bf16(a, b, facc[n], 0, 0, 0);
            }
        }
    }
#pragma unroll
    for (int n = 0; n < 4; ++n) {
        float bf = b_fuse[(nb + n) * 16 + lo];
#pragma unroll
        for (int r = 0; r < 4; ++r) {
            int node = n0 + m * 16 + hi * 4 + r;
            if (node < NODES)
                out[(size_t)node * FDIM + (nb + n) * 16 + lo] = facc[n][r] + bf;
        }
    }
}

extern "C" void kernel_launch(void* const* d_in, const int* in_sizes, int n_in,
                              void* d_out, int out_size, void* d_ws, size_t ws_size,
                              hipStream_t stream) {
    (void)in_sizes; (void)n_in; (void)out_size;
    const float* X      = (const float*)d_in[0];
    const int*   erow   = (const int*)d_in[1];
    const int*   ecol   = (const int*)d_in[2];
    const float* ew     = (const float*)d_in[3];
    const float* W_band = (const float*)d_in[4];
    const float* b_band = (const float*)d_in[5];
    const float* W_fuse = (const float*)d_in[6];
    const float* b_fuse = (const float*)d_in[7];
    float* out = (float*)d_out;

    float* psi    = (float*)d_ws;                           // 8*N*128 f32
    int*   rowptr = (int*)(psi + (size_t)8 * NODES * FDIM); // N+1
    int*   cursor = rowptr + NODES + 1;                     // N
    int*   ccol   = cursor + NODES;                         // E
    float* cw     = (float*)(ccol + NEDGE);                 // E
    size_t needed = ((size_t)8 * NODES * FDIM + NODES + 1 + NODES) * 4
                  + (size_t)NEDGE * 8;
    if (ws_size < needed) return;

    // CSR build
    hipMemsetAsync(cursor, 0, NODES * sizeof(int), stream);
    hist_kernel<<<(NEDGE + 255) / 256, 256, 0, stream>>>(erow, cursor, NEDGE);
    scan_kernel<<<1, 1024, 0, stream>>>(cursor, rowptr, NODES);
    hipMemcpyAsync(cursor, rowptr, NODES * sizeof(int), hipMemcpyDeviceToDevice, stream);
    scatter_kernel<<<(NEDGE + 255) / 256, 256, 0, stream>>>(erow, ecol, ew, cursor, ccol, cw, NEDGE);

    // Chebyshev recurrence: Psi_1 = S X ; Psi_k = 2 S Psi_{k-1} - Psi_{k-2}
    spmm2<<<NODES / 4, 256, 0, stream>>>(rowptr, ccol, cw, X, nullptr, psi, 1.0f, NODES);
    for (int k = 2; k <= 8; ++k) {
        const float* pin  = psi + (size_t)(k - 2) * NODES * FDIM;
        const float* psub = (k == 2) ? X : psi + (size_t)(k - 3) * NODES * FDIM;
        float*       pout = psi + (size_t)(k - 1) * NODES * FDIM;
        spmm2<<<NODES / 4, 256, 0, stream>>>(rowptr, ccol, cw, pin, psub, pout, 2.0f, NODES);
    }

    // bands + band GEMMs + fuse GEMM (bf16 MFMA, f32 accum)
    epilogue_kernel<<<(NODES + 31) / 32, 256, 0, stream>>>(
        X, psi, W_band, b_band, W_fuse, b_fuse, out);
}

// Round 5
// 757.168 us; speedup vs baseline: 1.0048x; 1.0048x over previous
//
#include <hip/hip_runtime.h>

#define NODES 50000
#define NEDGE 800000
#define FDIM  128

typedef __bf16 bf16x8 __attribute__((ext_vector_type(8)));
typedef float  f32x4  __attribute__((ext_vector_type(4)));

// Band coefficients B[i][k] = A[i][k] - A[i+1][k] (i=0..2), B[3] = A[3] (verified round 1).
__device__ __constant__ float BCOEF[4][9] = {
  { 0.35496460f,  0.31284160f, -0.03870412f,  0.00320868f, -1.99927e-4f,
    9.97480e-6f, -4.15015e-7f,  1.48054e-8f, -4.62272e-10f },
  { 0.27760180f,  0.12523720f, -0.11205788f,  0.03283760f, -0.00637710f,
    9.58661e-4f, -1.19074e-4f,  1.26613e-5f, -1.17878e-6f },
  { 0.16043170f, -0.08057710f, -0.08449120f,  0.08620240f, -0.04530300f,
    0.01752000f, -0.00553870f,  0.00150130f, -3.58171e-4f },
  { 0.20700190f, -0.35750170f,  0.23525320f, -0.12224870f,  0.05188000f,
   -0.01848860f,  0.00565820f, -0.00151400f,  3.59350e-4f }
};

__global__ void hist_kernel(const int* __restrict__ row, int* __restrict__ cnt, int e) {
    int i = blockIdx.x * blockDim.x + threadIdx.x;
    if (i < e) atomicAdd(&cnt[row[i]], 1);
}

__global__ void scan_kernel(const int* __restrict__ cnt, int* __restrict__ rowptr, int n) {
    __shared__ int buf[1024];
    __shared__ int carry;
    int tid = threadIdx.x;
    if (tid == 0) carry = 0;
    for (int base = 0; base < n; base += 1024) {
        int i = base + tid;
        int v = (i < n) ? cnt[i] : 0;
        __syncthreads();
        buf[tid] = v;
        __syncthreads();
        for (int off = 1; off < 1024; off <<= 1) {
            int t = (tid >= off) ? buf[tid - off] : 0;
            __syncthreads();
            buf[tid] += t;
            __syncthreads();
        }
        int incl = buf[tid];
        int c = carry;
        if (i < n) rowptr[i] = c + incl - v;
        __syncthreads();
        if (tid == 1023) carry = c + incl;
    }
    __syncthreads();
    if (tid == 0) rowptr[n] = carry;
}

__global__ void scatter_kernel(const int* __restrict__ row, const int* __restrict__ col,
                               const float* __restrict__ w, int* __restrict__ cursor,
                               int* __restrict__ ccol, float* __restrict__ cw, int e) {
    int i = blockIdx.x * blockDim.x + threadIdx.x;
    if (i < e) {
        int r = row[i];
        int pos = atomicAdd(&cursor[r], 1);
        ccol[pos] = col[i];
        cw[pos]  = w[i];
    }
}

// wave-per-row SpMM: lane holds features (2*lane, 2*lane+1); edge loop unrolled x4
// for 4 outstanding gathers (was 1 -> latency-bound at ~160us/dispatch).
__global__ __launch_bounds__(256) void spmm2(
    const int* __restrict__ rowptr, const int* __restrict__ cols,
    const float* __restrict__ wts, const float* __restrict__ pin,
    const float* __restrict__ psub, float* __restrict__ pout,
    float alpha, int n)
{
    int row = blockIdx.x * 4 + (threadIdx.x >> 6);
    if (row >= n) return;
    int lane = threadIdx.x & 63;
    int s = rowptr[row], e = rowptr[row + 1];
    const float2* pin2 = reinterpret_cast<const float2*>(pin);
    float ax0 = 0.f, ay0 = 0.f, ax1 = 0.f, ay1 = 0.f;
    float ax2 = 0.f, ay2 = 0.f, ax3 = 0.f, ay3 = 0.f;
    int i = s;
    for (; i + 4 <= e; i += 4) {
        int c0 = cols[i], c1 = cols[i + 1], c2 = cols[i + 2], c3 = cols[i + 3];
        float w0 = wts[i], w1 = wts[i + 1], w2 = wts[i + 2], w3 = wts[i + 3];
        float2 v0 = pin2[(size_t)c0 * 64 + lane];
        float2 v1 = pin2[(size_t)c1 * 64 + lane];
        float2 v2 = pin2[(size_t)c2 * 64 + lane];
        float2 v3 = pin2[(size_t)c3 * 64 + lane];
        ax0 += w0 * v0.x; ay0 += w0 * v0.y;
        ax1 += w1 * v1.x; ay1 += w1 * v1.y;
        ax2 += w2 * v2.x; ay2 += w2 * v2.y;
        ax3 += w3 * v3.x; ay3 += w3 * v3.y;
    }
    for (; i < e; ++i) {
        int c = cols[i]; float wv = wts[i];
        float2 v = pin2[(size_t)c * 64 + lane];
        ax0 += wv * v.x; ay0 += wv * v.y;
    }
    float rx = alpha * ((ax0 + ax1) + (ax2 + ax3));
    float ry = alpha * ((ay0 + ay1) + (ay2 + ay3));
    size_t off = (size_t)row * 64 + lane;
    if (psub) {
        float2 sv = reinterpret_cast<const float2*>(psub)[off];
        rx -= sv.x; ry -= sv.y;
    }
    reinterpret_cast<float2*>(pout)[off] = make_float2(rx, ry);
}

// ---------------- MFMA epilogue ----------------
// LDS map (16B chunks): slots 0..3 = bands_i -> H_i [32][128] bf16, slot 4 = X bf16,
// then Wt (transposed weights) [128 o][128 k] bf16. XOR swizzle c ^= (row&15) makes
// all ds_read_b128 fragment reads <=2-way bank aliased (free per m136).
#define RIDX(s, r, c) ((((s) << 9) + ((r) << 4) + ((c) ^ ((r) & 15))) << 3)
#define WIDX(o, c)    (((2560 + ((o) << 4) + ((c) ^ ((o) & 15)))) << 3)

__device__ __forceinline__ void stage_wt(const float* __restrict__ Wsrc, __bf16* SW) {
    // Wsrc: [128 k][128 o] f32 row-major -> LDS Wt[o][k] bf16 (swizzled)
    for (int it = 0; it < 8; ++it) {
        int task = it * 256 + threadIdx.x;   // 0..2047
        int o = task & 127, c = task >> 7;   // chunk c covers k = c*8..c*8+7
        const float* colp = Wsrc + (size_t)(c * 8) * 128 + o;
        bf16x8 v;
#pragma unroll
        for (int j = 0; j < 8; ++j) v[j] = (__bf16)colp[(size_t)j * 128];
        *reinterpret_cast<bf16x8*>(&SW[WIDX(o, c)]) = v;
    }
}

__global__ __launch_bounds__(256) void epilogue_kernel(
    const float* __restrict__ X,        // [N][128]
    const float* __restrict__ psi,      // [8][N][128]
    const float* __restrict__ W_band,   // [4][128][128]
    const float* __restrict__ b_band,   // [4][128]
    const float* __restrict__ W_fuse,   // [640][128]
    const float* __restrict__ b_fuse,   // [128]
    float* __restrict__ out)            // [N][128]
{
    __shared__ __align__(16) __bf16 SW[36864];   // 72 KB -> 2 blocks/CU
    const int tid = threadIdx.x;
    const int n0 = blockIdx.x * 32;

    // Phase 1: bands (f32 combine of 9 Psi arrays) -> bf16 LDS; X -> bf16 LDS slot 4.
    for (int t = tid; t < 512; t += 256) {
        int row = t >> 4, c = t & 15;
        int node = n0 + row;
        bool ok = node < NODES;
        float bacc[4][8];
#pragma unroll
        for (int i = 0; i < 4; ++i)
#pragma unroll
            for (int j = 0; j < 8; ++j) bacc[i][j] = 0.f;
#pragma unroll
        for (int k = 0; k <= 8; ++k) {
            const float* src = (k == 0)
                ? X + (size_t)node * FDIM + c * 8
                : psi + ((size_t)(k - 1) * NODES + node) * FDIM + c * 8;
            float4 q0 = make_float4(0.f, 0.f, 0.f, 0.f), q1 = q0;
            if (ok) {
                q0 = reinterpret_cast<const float4*>(src)[0];
                q1 = reinterpret_cast<const float4*>(src)[1];
            }
            float pk[8] = {q0.x, q0.y, q0.z, q0.w, q1.x, q1.y, q1.z, q1.w};
            if (k == 0) {
                bf16x8 xv;
#pragma unroll
                for (int j = 0; j < 8; ++j) xv[j] = (__bf16)pk[j];
                *reinterpret_cast<bf16x8*>(&SW[RIDX(4, row, c)]) = xv;
            }
#pragma unroll
            for (int i = 0; i < 4; ++i)
#pragma unroll
                for (int j = 0; j < 8; ++j) bacc[i][j] += BCOEF[i][k] * pk[j];
        }
#pragma unroll
        for (int i = 0; i < 4; ++i) {
            bf16x8 bv;
#pragma unroll
            for (int j = 0; j < 8; ++j) bv[j] = (__bf16)bacc[i][j];
            *reinterpret_cast<bf16x8*>(&SW[RIDX(i, row, c)]) = bv;
        }
    }

    const int l  = tid & 63, w = tid >> 6;
    const int lo = l & 15, hi = l >> 4;
    const int m  = w & 1, nb = (w >> 1) * 4;   // wave -> (M-tile, 4 N-tiles)

    // Phase 2: per-band GEMM H_i = relu(bands_i @ W_i + b_i), H_i overwrites bands_i.
    for (int i = 0; i < 4; ++i) {
        __syncthreads();                       // R_i ready / prev Wt reads done
        stage_wt(W_band + (size_t)i * 128 * 128, SW);
        __syncthreads();
        f32x4 hacc[4];
#pragma unroll
        for (int n = 0; n < 4; ++n) hacc[n] = (f32x4){0.f, 0.f, 0.f, 0.f};
#pragma unroll
        for (int k = 0; k < 4; ++k) {
            bf16x8 a = *reinterpret_cast<const bf16x8*>(&SW[RIDX(i, m * 16 + lo, k * 4 + hi)]);
#pragma unroll
            for (int n = 0; n < 4; ++n) {
                bf16x8 b = *reinterpret_cast<const bf16x8*>(&SW[WIDX((nb + n) * 16 + lo, k * 4 + hi)]);
                hacc[n] = __builtin_amdgcn_mfma_f32_16x16x32_bf16(a, b, hacc[n], 0, 0, 0);
            }
        }
        __syncthreads();                       // all reads of R_i done before overwrite
#pragma unroll
        for (int n = 0; n < 4; ++n) {
            float bb = b_band[i * 128 + (nb + n) * 16 + lo];
#pragma unroll
            for (int r = 0; r < 4; ++r) {
                float h = hacc[n][r] + bb;
                h = h > 0.f ? h : 0.f;
                int row = m * 16 + hi * 4 + r;
                int o   = (nb + n) * 16 + lo;
                SW[((i << 9) + (row << 4) + (((o >> 3)) ^ (row & 15))) * 8 + (o & 7)] = (__bf16)h;
            }
        }
    }

    // Phase 3: fuse GEMM over K=640 = slots {H0,H1,H2,H3,X} x 128.
    f32x4 facc[4];
#pragma unroll
    for (int n = 0; n < 4; ++n) facc[n] = (f32x4){0.f, 0.f, 0.f, 0.f};
    for (int kc = 0; kc < 5; ++kc) {
        __syncthreads();                       // prev Wt reads / H writes done
        stage_wt(W_fuse + (size_t)kc * 128 * 128, SW);
        __syncthreads();
#pragma unroll
        for (int k = 0; k < 4; ++k) {
            bf16x8 a = *reinterpret_cast<const bf16x8*>(&SW[RIDX(kc, m * 16 + lo, k * 4 + hi)]);
#pragma unroll
            for (int n = 0; n < 4; ++n) {
                bf16x8 b = *reinterpret_cast<const bf16x8*>(&SW[WIDX((nb + n) * 16 + lo, k * 4 + hi)]);
                facc[n] = __builtin_amdgcn_mfma_f32_16x16x32_bf16(a, b, facc[n], 0, 0, 0);
            }
        }
    }
#pragma unroll
    for (int n = 0; n < 4; ++n) {
        float bf = b_fuse[(nb + n) * 16 + lo];
#pragma unroll
        for (int r = 0; r < 4; ++r) {
            int node = n0 + m * 16 + hi * 4 + r;
            if (node < NODES)
                out[(size_t)node * FDIM + (nb + n) * 16 + lo] = facc[n][r] + bf;
        }
    }
}

extern "C" void kernel_launch(void* const* d_in, const int* in_sizes, int n_in,
                              void* d_out, int out_size, void* d_ws, size_t ws_size,
                              hipStream_t stream) {
    (void)in_sizes; (void)n_in; (void)out_size;
    const float* X      = (const float*)d_in[0];
    const int*   erow   = (const int*)d_in[1];
    const int*   ecol   = (const int*)d_in[2];
    const float* ew     = (const float*)d_in[3];
    const float* W_band = (const float*)d_in[4];
    const float* b_band = (const float*)d_in[5];
    const float* W_fuse = (const float*)d_in[6];
    const float* b_fuse = (const float*)d_in[7];
    float* out = (float*)d_out;

    float* psi    = (float*)d_ws;                           // 8*N*128 f32
    int*   rowptr = (int*)(psi + (size_t)8 * NODES * FDIM); // N+1
    int*   cursor = rowptr + NODES + 1;                     // N
    int*   ccol   = cursor + NODES;                         // E
    float* cw     = (float*)(ccol + NEDGE);                 // E
    size_t needed = ((size_t)8 * NODES * FDIM + NODES + 1 + NODES) * 4
                  + (size_t)NEDGE * 8;
    if (ws_size < needed) return;

    // CSR build
    hipMemsetAsync(cursor, 0, NODES * sizeof(int), stream);
    hist_kernel<<<(NEDGE + 255) / 256, 256, 0, stream>>>(erow, cursor, NEDGE);
    scan_kernel<<<1, 1024, 0, stream>>>(cursor, rowptr, NODES);
    hipMemcpyAsync(cursor, rowptr, NODES * sizeof(int), hipMemcpyDeviceToDevice, stream);
    scatter_kernel<<<(NEDGE + 255) / 256, 256, 0, stream>>>(erow, ecol, ew, cursor, ccol, cw, NEDGE);

    // Chebyshev recurrence: Psi_1 = S X ; Psi_k = 2 S Psi_{k-1} - Psi_{k-2}
    spmm2<<<NODES / 4, 256, 0, stream>>>(rowptr, ccol, cw, X, nullptr, psi, 1.0f, NODES);
    for (int k = 2; k <= 8; ++k) {
        const float* pin  = psi + (size_t)(k - 2) * NODES * FDIM;
        const float* psub = (k == 2) ? X : psi + (size_t)(k - 3) * NODES * FDIM;
        float*       pout = psi + (size_t)(k - 1) * NODES * FDIM;
        spmm2<<<NODES / 4, 256, 0, stream>>>(rowptr, ccol, cw, pin, psub, pout, 2.0f, NODES);
    }

    // bands + band GEMMs + fuse GEMM (bf16 MFMA, f32 accum)
    epilogue_kernel<<<(NODES + 31) / 32, 256, 0, stream>>>(
        X, psi, W_band, b_band, W_fuse, b_fuse, out);
}

// Round 6
// 705.074 us; speedup vs baseline: 1.0790x; 1.0739x over previous
//
#include <hip/hip_runtime.h>

#define NODES 50000
#define NEDGE 800000
#define FDIM  128

typedef __bf16 bf16x8 __attribute__((ext_vector_type(8)));
typedef float  f32x4  __attribute__((ext_vector_type(4)));

// Band coefficients B[i][k] = A[i][k] - A[i+1][k] (i=0..2), B[3] = A[3] (verified round 1).
__device__ __constant__ float BCOEF[4][9] = {
  { 0.35496460f,  0.31284160f, -0.03870412f,  0.00320868f, -1.99927e-4f,
    9.97480e-6f, -4.15015e-7f,  1.48054e-8f, -4.62272e-10f },
  { 0.27760180f,  0.12523720f, -0.11205788f,  0.03283760f, -0.00637710f,
    9.58661e-4f, -1.19074e-4f,  1.26613e-5f, -1.17878e-6f },
  { 0.16043170f, -0.08057710f, -0.08449120f,  0.08620240f, -0.04530300f,
    0.01752000f, -0.00553870f,  0.00150130f, -3.58171e-4f },
  { 0.20700190f, -0.35750170f,  0.23525320f, -0.12224870f,  0.05188000f,
   -0.01848860f,  0.00565820f, -0.00151400f,  3.59350e-4f }
};

__global__ void hist_kernel(const int* __restrict__ row, int* __restrict__ cnt, int e) {
    int i = blockIdx.x * blockDim.x + threadIdx.x;
    if (i < e) atomicAdd(&cnt[row[i]], 1);
}

// single-block exclusive scan, wave-shuffle based (3 barriers/iter vs 20 before)
__global__ __launch_bounds__(1024) void scan_kernel(
    const int* __restrict__ cnt, int* __restrict__ rowptr, int n)
{
    __shared__ int wsum[16];
    __shared__ int carry;
    const int tid = threadIdx.x, lane = tid & 63, wv = tid >> 6;
    if (tid == 0) carry = 0;
    for (int base = 0; base < n; base += 1024) {
        int i = base + tid;
        int v = (i < n) ? cnt[i] : 0;
        int x = v;                         // wave inclusive scan
#pragma unroll
        for (int off = 1; off < 64; off <<= 1) {
            int t = __shfl_up(x, off);
            if (lane >= off) x += t;
        }
        if (lane == 63) wsum[wv] = x;
        __syncthreads();                   // (1) wsum raw ready
        if (tid < 16) {
            int s = wsum[tid];
#pragma unroll
            for (int off = 1; off < 16; off <<= 1) {
                int t = __shfl_up(s, off);
                if (tid >= off) s += t;
            }
            wsum[tid] = s;                 // inclusive scan of wave sums
        }
        __syncthreads();                   // (2) scanned wsum + carry stable
        int wbase = wv ? wsum[wv - 1] : 0;
        int c = carry;
        if (i < n) rowptr[i] = c + wbase + x - v;
        __syncthreads();                   // (3) everyone done reading carry/wsum
        if (tid == 1023) carry = c + wbase + x;
    }
    __syncthreads();
    if (tid == 0) rowptr[n] = carry;
}

__global__ void scatter_kernel(const int* __restrict__ row, const int* __restrict__ col,
                               const float* __restrict__ w, int* __restrict__ cursor,
                               int2* __restrict__ ev, int e) {
    int i = blockIdx.x * blockDim.x + threadIdx.x;
    if (i < e) {
        int r = row[i];
        int pos = atomicAdd(&cursor[r], 1);
        ev[pos] = make_int2(col[i], __float_as_int(w[i]));
    }
}

// wave-per-row SpMM, interleaved int2 edges, 8 outstanding gathers.
__global__ __launch_bounds__(256) void spmm3(
    const int* __restrict__ rowptr, const int2* __restrict__ ev,
    const float* __restrict__ pin, const float* __restrict__ psub,
    float* __restrict__ pout, float alpha, int n)
{
    int row = blockIdx.x * 4 + (threadIdx.x >> 6);
    if (row >= n) return;
    int lane = threadIdx.x & 63;
    int s = rowptr[row], e = rowptr[row + 1];
    const float2* pin2 = reinterpret_cast<const float2*>(pin);
    float ax[8], ay[8];
#pragma unroll
    for (int j = 0; j < 8; ++j) { ax[j] = 0.f; ay[j] = 0.f; }
    int i = s;
    for (; i + 8 <= e; i += 8) {
        int2 ed[8];
#pragma unroll
        for (int j = 0; j < 8; ++j) ed[j] = ev[i + j];
#pragma unroll
        for (int j = 0; j < 8; ++j) {
            float2 v = pin2[(size_t)ed[j].x * 64 + lane];
            float w = __int_as_float(ed[j].y);
            ax[j] += w * v.x; ay[j] += w * v.y;
        }
    }
    if (i + 4 <= e) {
        int2 ed[4];
#pragma unroll
        for (int j = 0; j < 4; ++j) ed[j] = ev[i + j];
#pragma unroll
        for (int j = 0; j < 4; ++j) {
            float2 v = pin2[(size_t)ed[j].x * 64 + lane];
            float w = __int_as_float(ed[j].y);
            ax[j] += w * v.x; ay[j] += w * v.y;
        }
        i += 4;
    }
    for (; i < e; ++i) {
        int2 ed = ev[i];
        float2 v = pin2[(size_t)ed.x * 64 + lane];
        float w = __int_as_float(ed.y);
        ax[0] += w * v.x; ay[0] += w * v.y;
    }
    float rx = ((ax[0] + ax[1]) + (ax[2] + ax[3])) + ((ax[4] + ax[5]) + (ax[6] + ax[7]));
    float ry = ((ay[0] + ay[1]) + (ay[2] + ay[3])) + ((ay[4] + ay[5]) + (ay[6] + ay[7]));
    rx *= alpha; ry *= alpha;
    size_t off = (size_t)row * 64 + lane;
    if (psub) {
        float2 sv = reinterpret_cast<const float2*>(psub)[off];
        rx -= sv.x; ry -= sv.y;
    }
    reinterpret_cast<float2*>(pout)[off] = make_float2(rx, ry);
}

// ---------------- MFMA epilogue (512 threads, 32-node tile) ----------------
// LDS map (16B chunks): slots 0..3 = bands_i -> H_i [32][128] bf16, slot 4 = X bf16,
// then Wt (transposed weights) [128 o][128 k] bf16. XOR swizzle c ^= (row&15) makes
// all ds_read_b128 fragment reads <=2-way bank aliased (free per m136).
#define RIDX(s, r, c) ((((s) << 9) + ((r) << 4) + ((c) ^ ((r) & 15))) << 3)
#define WIDX(o, c)    (((2560 + ((o) << 4) + ((c) ^ ((o) & 15)))) << 3)

__device__ __forceinline__ void stage_wt512(const float* __restrict__ Wsrc, __bf16* SW) {
    // Wsrc: [128 k][128 o] f32 row-major -> LDS Wt[o][k] bf16 (swizzled)
    for (int it = 0; it < 4; ++it) {
        int task = it * 512 + threadIdx.x;   // 0..2047
        int o = task & 127, c = task >> 7;   // chunk c covers k = c*8..c*8+7
        const float* colp = Wsrc + (size_t)(c * 8) * 128 + o;
        bf16x8 v;
#pragma unroll
        for (int j = 0; j < 8; ++j) v[j] = (__bf16)colp[(size_t)j * 128];
        *reinterpret_cast<bf16x8*>(&SW[WIDX(o, c)]) = v;
    }
}

__global__ __launch_bounds__(512, 4) void epilogue_kernel(
    const float* __restrict__ X,        // [N][128]
    const float* __restrict__ psi,      // [8][N][128]
    const float* __restrict__ W_band,   // [4][128][128]
    const float* __restrict__ b_band,   // [4][128]
    const float* __restrict__ W_fuse,   // [640][128]
    const float* __restrict__ b_fuse,   // [128]
    float* __restrict__ out)            // [N][128]
{
    __shared__ __align__(16) __bf16 SW[36864];   // 72 KB -> 2 blocks/CU, 16 waves/CU
    const int tid = threadIdx.x;
    const int n0 = blockIdx.x * 32;

    // Phase 1: bands (f32 combine of 9 Psi arrays) -> bf16 LDS; X -> bf16 LDS slot 4.
    {
        int row = tid >> 4, c = tid & 15;    // 512 threads = 512 tasks
        int node = n0 + row;
        bool ok = node < NODES;
        float bacc[4][8];
#pragma unroll
        for (int i = 0; i < 4; ++i)
#pragma unroll
            for (int j = 0; j < 8; ++j) bacc[i][j] = 0.f;
#pragma unroll
        for (int k = 0; k <= 8; ++k) {
            const float* src = (k == 0)
                ? X + (size_t)node * FDIM + c * 8
                : psi + ((size_t)(k - 1) * NODES + node) * FDIM + c * 8;
            float4 q0 = make_float4(0.f, 0.f, 0.f, 0.f), q1 = q0;
            if (ok) {
                q0 = reinterpret_cast<const float4*>(src)[0];
                q1 = reinterpret_cast<const float4*>(src)[1];
            }
            float pk[8] = {q0.x, q0.y, q0.z, q0.w, q1.x, q1.y, q1.z, q1.w};
            if (k == 0) {
                bf16x8 xv;
#pragma unroll
                for (int j = 0; j < 8; ++j) xv[j] = (__bf16)pk[j];
                *reinterpret_cast<bf16x8*>(&SW[RIDX(4, row, c)]) = xv;
            }
#pragma unroll
            for (int i = 0; i < 4; ++i)
#pragma unroll
                for (int j = 0; j < 8; ++j) bacc[i][j] += BCOEF[i][k] * pk[j];
        }
#pragma unroll
        for (int i = 0; i < 4; ++i) {
            bf16x8 bv;
#pragma unroll
            for (int j = 0; j < 8; ++j) bv[j] = (__bf16)bacc[i][j];
            *reinterpret_cast<bf16x8*>(&SW[RIDX(i, row, c)]) = bv;
        }
    }

    const int l  = tid & 63, w = tid >> 6;   // 8 waves
    const int lo = l & 15, hi = l >> 4;
    const int m  = w & 1, nb = (w >> 1) * 2; // wave -> (M-tile, 2 N-tiles)

    // Phase 2: per-band GEMM H_i = relu(bands_i @ W_i + b_i), H_i overwrites bands_i.
    for (int i = 0; i < 4; ++i) {
        __syncthreads();                     // R_i ready / prev Wt reads done
        stage_wt512(W_band + (size_t)i * 128 * 128, SW);
        __syncthreads();
        f32x4 hacc[2];
#pragma unroll
        for (int n = 0; n < 2; ++n) hacc[n] = (f32x4){0.f, 0.f, 0.f, 0.f};
#pragma unroll
        for (int k = 0; k < 4; ++k) {
            bf16x8 a = *reinterpret_cast<const bf16x8*>(&SW[RIDX(i, m * 16 + lo, k * 4 + hi)]);
#pragma unroll
            for (int n = 0; n < 2; ++n) {
                bf16x8 b = *reinterpret_cast<const bf16x8*>(&SW[WIDX((nb + n) * 16 + lo, k * 4 + hi)]);
                hacc[n] = __builtin_amdgcn_mfma_f32_16x16x32_bf16(a, b, hacc[n], 0, 0, 0);
            }
        }
        __syncthreads();                     // all reads of R_i done before overwrite
#pragma unroll
        for (int n = 0; n < 2; ++n) {
            float bb = b_band[i * 128 + (nb + n) * 16 + lo];
#pragma unroll
            for (int r = 0; r < 4; ++r) {
                float h = hacc[n][r] + bb;
                h = h > 0.f ? h : 0.f;
                int row = m * 16 + hi * 4 + r;
                int o   = (nb + n) * 16 + lo;
                SW[((i << 9) + (row << 4) + (((o >> 3)) ^ (row & 15))) * 8 + (o & 7)] = (__bf16)h;
            }
        }
    }

    // Phase 3: fuse GEMM over K=640 = slots {H0,H1,H2,H3,X} x 128.
    f32x4 facc[2];
#pragma unroll
    for (int n = 0; n < 2; ++n) facc[n] = (f32x4){0.f, 0.f, 0.f, 0.f};
    for (int kc = 0; kc < 5; ++kc) {
        __syncthreads();                     // prev Wt reads / H writes done
        stage_wt512(W_fuse + (size_t)kc * 128 * 128, SW);
        __syncthreads();
#pragma unroll
        for (int k = 0; k < 4; ++k) {
            bf16x8 a = *reinterpret_cast<const bf16x8*>(&SW[RIDX(kc, m * 16 + lo, k * 4 + hi)]);
#pragma unroll
            for (int n = 0; n < 2; ++n) {
                bf16x8 b = *reinterpret_cast<const bf16x8*>(&SW[WIDX((nb + n) * 16 + lo, k * 4 + hi)]);
                facc[n] = __builtin_amdgcn_mfma_f32_16x16x32_bf16(a, b, facc[n], 0, 0, 0);
            }
        }
    }
#pragma unroll
    for (int n = 0; n < 2; ++n) {
        float bf = b_fuse[(nb + n) * 16 + lo];
#pragma unroll
        for (int r = 0; r < 4; ++r) {
            int node = n0 + m * 16 + hi * 4 + r;
            if (node < NODES)
                out[(size_t)node * FDIM + (nb + n) * 16 + lo] = facc[n][r] + bf;
        }
    }
}

extern "C" void kernel_launch(void* const* d_in, const int* in_sizes, int n_in,
                              void* d_out, int out_size, void* d_ws, size_t ws_size,
                              hipStream_t stream) {
    (void)in_sizes; (void)n_in; (void)out_size;
    const float* X      = (const float*)d_in[0];
    const int*   erow   = (const int*)d_in[1];
    const int*   ecol   = (const int*)d_in[2];
    const float* ew     = (const float*)d_in[3];
    const float* W_band = (const float*)d_in[4];
    const float* b_band = (const float*)d_in[5];
    const float* W_fuse = (const float*)d_in[6];
    const float* b_fuse = (const float*)d_in[7];
    float* out = (float*)d_out;

    float* psi    = (float*)d_ws;                           // 8*N*128 f32
    int*   rowptr = (int*)(psi + (size_t)8 * NODES * FDIM); // N+1
    int*   cursor = rowptr + NODES + 1;                     // N
    int2*  ev     = (int2*)(cursor + NODES);                // E (col, w) interleaved
    size_t needed = ((size_t)8 * NODES * FDIM + NODES + 1 + NODES) * 4
                  + (size_t)NEDGE * 8;
    if (ws_size < needed) return;

    // CSR build
    hipMemsetAsync(cursor, 0, NODES * sizeof(int), stream);
    hist_kernel<<<(NEDGE + 255) / 256, 256, 0, stream>>>(erow, cursor, NEDGE);
    scan_kernel<<<1, 1024, 0, stream>>>(cursor, rowptr, NODES);
    hipMemcpyAsync(cursor, rowptr, NODES * sizeof(int), hipMemcpyDeviceToDevice, stream);
    scatter_kernel<<<(NEDGE + 255) / 256, 256, 0, stream>>>(erow, ecol, ew, cursor, ev, NEDGE);

    // Chebyshev recurrence: Psi_1 = S X ; Psi_k = 2 S Psi_{k-1} - Psi_{k-2}
    spmm3<<<NODES / 4, 256, 0, stream>>>(rowptr, ev, X, nullptr, psi, 1.0f, NODES);
    for (int k = 2; k <= 8; ++k) {
        const float* pin  = psi + (size_t)(k - 2) * NODES * FDIM;
        const float* psub = (k == 2) ? X : psi + (size_t)(k - 3) * NODES * FDIM;
        float*       pout = psi + (size_t)(k - 1) * NODES * FDIM;
        spmm3<<<NODES / 4, 256, 0, stream>>>(rowptr, ev, pin, psub, pout, 2.0f, NODES);
    }

    // bands + band GEMMs + fuse GEMM (bf16 MFMA, f32 accum)
    epilogue_kernel<<<(NODES + 31) / 32, 512, 0, stream>>>(
        X, psi, W_band, b_band, W_fuse, b_fuse, out);
}

// Round 7
// 500.759 us; speedup vs baseline: 1.5193x; 1.4080x over previous
//
#include <hip/hip_runtime.h>

#define NODES 50000
#define NEDGE 800000
#define FDIM  128

typedef __bf16 bf16x8 __attribute__((ext_vector_type(8)));
typedef float  f32x4  __attribute__((ext_vector_type(4)));

// Band coefficients B[i][k] = A[i][k] - A[i+1][k] (i=0..2), B[3] = A[3] (verified round 1).
__device__ __constant__ float BCOEF[4][9] = {
  { 0.35496460f,  0.31284160f, -0.03870412f,  0.00320868f, -1.99927e-4f,
    9.97480e-6f, -4.15015e-7f,  1.48054e-8f, -4.62272e-10f },
  { 0.27760180f,  0.12523720f, -0.11205788f,  0.03283760f, -0.00637710f,
    9.58661e-4f, -1.19074e-4f,  1.26613e-5f, -1.17878e-6f },
  { 0.16043170f, -0.08057710f, -0.08449120f,  0.08620240f, -0.04530300f,
    0.01752000f, -0.00553870f,  0.00150130f, -3.58171e-4f },
  { 0.20700190f, -0.35750170f,  0.23525320f, -0.12224870f,  0.05188000f,
   -0.01848860f,  0.00565820f, -0.00151400f,  3.59350e-4f }
};

__device__ __forceinline__ ushort bfbits(float f) {
    union { __bf16 b; ushort u; } cv; cv.b = (__bf16)f; return cv.u;
}

__device__ __forceinline__ void gload_lds16(const void* g, void* l) {
    __builtin_amdgcn_global_load_lds(
        (const __attribute__((address_space(1))) void*)(g),
        (__attribute__((address_space(3))) void*)(l),
        16, 0, 0);
}

__global__ void hist_kernel(const int* __restrict__ row, int* __restrict__ cnt, int e) {
    int i = blockIdx.x * blockDim.x + threadIdx.x;
    if (i < e) atomicAdd(&cnt[row[i]], 1);
}

// single-block exclusive scan, wave-shuffle based
__global__ __launch_bounds__(1024) void scan_kernel(
    const int* __restrict__ cnt, int* __restrict__ rowptr, int n)
{
    __shared__ int wsum[16];
    __shared__ int carry;
    const int tid = threadIdx.x, lane = tid & 63, wv = tid >> 6;
    if (tid == 0) carry = 0;
    for (int base = 0; base < n; base += 1024) {
        int i = base + tid;
        int v = (i < n) ? cnt[i] : 0;
        int x = v;
#pragma unroll
        for (int off = 1; off < 64; off <<= 1) {
            int t = __shfl_up(x, off);
            if (lane >= off) x += t;
        }
        if (lane == 63) wsum[wv] = x;
        __syncthreads();
        if (tid < 16) {
            int s = wsum[tid];
#pragma unroll
            for (int off = 1; off < 16; off <<= 1) {
                int t = __shfl_up(s, off);
                if (tid >= off) s += t;
            }
            wsum[tid] = s;
        }
        __syncthreads();
        int wbase = wv ? wsum[wv - 1] : 0;
        int c = carry;
        if (i < n) rowptr[i] = c + wbase + x - v;
        __syncthreads();
        if (tid == 1023) carry = c + wbase + x;
    }
    __syncthreads();
    if (tid == 0) rowptr[n] = carry;
}

__global__ void scatter_kernel(const int* __restrict__ row, const int* __restrict__ col,
                               const float* __restrict__ w, int* __restrict__ cursor,
                               int2* __restrict__ ev, int e) {
    int i = blockIdx.x * blockDim.x + threadIdx.x;
    if (i < e) {
        int r = row[i];
        int pos = atomicAdd(&cursor[r], 1);
        ev[pos] = make_int2(col[i], __float_as_int(w[i]));
    }
}

// X f32 -> bf16 (4 elems/thread)
__global__ void prep_x(const float* __restrict__ X, ushort* __restrict__ Xb, int nq) {
    int i = blockIdx.x * blockDim.x + threadIdx.x;
    if (i >= nq) return;
    float4 v = reinterpret_cast<const float4*>(X)[i];
    ushort4 o;
    o.x = bfbits(v.x); o.y = bfbits(v.y); o.z = bfbits(v.z); o.w = bfbits(v.w);
    reinterpret_cast<ushort4*>(Xb)[i] = o;
}

// Weights: [mat][k][o] f32 -> Wp[mat][o][k] bf16 (transposed, un-swizzled; swizzle
// applied on the per-lane DMA source address at stage time).
__global__ void prep_w(const float* __restrict__ Wb, const float* __restrict__ Wf,
                       ushort* __restrict__ Wp) {
    int idx = blockIdx.x * blockDim.x + threadIdx.x;  // 9*128*128
    if (idx >= 9 * 128 * 128) return;
    int mat = idx >> 14, r = idx & 16383, o = r >> 7, k = r & 127;
    const float* src = (mat < 4) ? (Wb + mat * 16384 + k * 128 + o)
                                 : (Wf + (mat - 4) * 16384 + k * 128 + o);
    Wp[idx] = bfbits(*src);
}

// wave-per-row SpMM on bf16 features: lane reads 1 uint (2 bf16), f32 accumulate,
// 8 outstanding 256B gathers, bf16 store.
__global__ __launch_bounds__(256) void spmm4(
    const int* __restrict__ rowptr, const int2* __restrict__ ev,
    const ushort* __restrict__ pin, const ushort* __restrict__ psub,
    ushort* __restrict__ pout, float alpha, int n)
{
    int row = blockIdx.x * 4 + (threadIdx.x >> 6);
    if (row >= n) return;
    int lane = threadIdx.x & 63;
    int s = rowptr[row], e = rowptr[row + 1];
    const uint* pin1 = reinterpret_cast<const uint*>(pin);   // [n][64]
    float ax[8], ay[8];
#pragma unroll
    for (int j = 0; j < 8; ++j) { ax[j] = 0.f; ay[j] = 0.f; }
    int i = s;
    for (; i + 8 <= e; i += 8) {
        int2 ed[8];
#pragma unroll
        for (int j = 0; j < 8; ++j) ed[j] = ev[i + j];
#pragma unroll
        for (int j = 0; j < 8; ++j) {
            uint u = pin1[(size_t)ed[j].x * 64 + lane];
            float w = __int_as_float(ed[j].y);
            ax[j] += w * __uint_as_float(u << 16);
            ay[j] += w * __uint_as_float(u & 0xffff0000u);
        }
    }
    if (i + 4 <= e) {
        int2 ed[4];
#pragma unroll
        for (int j = 0; j < 4; ++j) ed[j] = ev[i + j];
#pragma unroll
        for (int j = 0; j < 4; ++j) {
            uint u = pin1[(size_t)ed[j].x * 64 + lane];
            float w = __int_as_float(ed[j].y);
            ax[j] += w * __uint_as_float(u << 16);
            ay[j] += w * __uint_as_float(u & 0xffff0000u);
        }
        i += 4;
    }
    for (; i < e; ++i) {
        int2 ed = ev[i];
        uint u = pin1[(size_t)ed.x * 64 + lane];
        float w = __int_as_float(ed.y);
        ax[0] += w * __uint_as_float(u << 16);
        ay[0] += w * __uint_as_float(u & 0xffff0000u);
    }
    float rx = ((ax[0] + ax[1]) + (ax[2] + ax[3])) + ((ax[4] + ax[5]) + (ax[6] + ax[7]));
    float ry = ((ay[0] + ay[1]) + (ay[2] + ay[3])) + ((ay[4] + ay[5]) + (ay[6] + ay[7]));
    rx *= alpha; ry *= alpha;
    size_t off = (size_t)row * 64 + lane;
    if (psub) {
        uint su = reinterpret_cast<const uint*>(psub)[off];
        rx -= __uint_as_float(su << 16);
        ry -= __uint_as_float(su & 0xffff0000u);
    }
    union { uint u; __bf16 b[2]; } pk;
    pk.b[0] = (__bf16)rx; pk.b[1] = (__bf16)ry;
    reinterpret_cast<uint*>(pout)[off] = pk.u;
}

// ---------------- MFMA epilogue (512 threads, 32-node tile) ----------------
// LDS (16B chunks): chunks 0..2559 = slots 0..3 (bands_i -> H_i) + slot 4 (X),
// [32 rows][16 chunks] each, XOR-swizzled (c ^= row&15). Chunks 2560..4607 = Wt
// [128 o][16 chunks], swizzled on read, staged linearly via global_load_lds from
// an inverse-swizzled per-lane source (rule #21).
#define RIDX(s, r, c) ((((s) << 9) + ((r) << 4) + ((c) ^ ((r) & 15))) << 3)
#define WIDX(o, c)    ((2560 + ((o) << 4) + ((c) ^ ((o) & 15))) << 3)

__global__ __launch_bounds__(512, 4) void epilogue_kernel(
    const ushort* __restrict__ Xb,      // [N][128] bf16
    const ushort* __restrict__ psi,     // [8][N][128] bf16
    const ushort* __restrict__ Wp,      // [9][128 o][128 k] bf16
    const float* __restrict__ b_band,   // [4][128]
    const float* __restrict__ b_fuse,   // [128]
    float* __restrict__ out)            // [N][128]
{
    __shared__ __align__(16) __bf16 SW[36864];   // 72 KB
    const int tid = threadIdx.x;
    const int n0 = blockIdx.x * 32;

    const int l  = tid & 63, w = tid >> 6;   // 8 waves
    const int lo = l & 15, hi = l >> 4;
    const int m  = w & 1, nb = (w >> 1) * 2; // wave -> (M-tile, 2 N-tiles)

    // preload biases
    float bb[4][2], bf[2];
#pragma unroll
    for (int i = 0; i < 4; ++i)
#pragma unroll
        for (int n = 0; n < 2; ++n) bb[i][n] = b_band[i * 128 + (nb + n) * 16 + lo];
#pragma unroll
    for (int n = 0; n < 2; ++n) bf[n] = b_fuse[(nb + n) * 16 + lo];

    // Phase 1: bands (f32 combine of bf16 X + 8 psi) -> bf16 LDS; X copied to slot 4.
    {
        int row = tid >> 4, c = tid & 15;
        int node = n0 + row;
        bool ok = node < NODES;
        uint4 z = make_uint4(0, 0, 0, 0);
        uint4 xq = ok ? reinterpret_cast<const uint4*>(Xb + (size_t)node * FDIM)[c] : z;
        *reinterpret_cast<uint4*>(&SW[RIDX(4, row, c)]) = xq;
        float f[8], bacc[4][8];
        {
            const uint* p = &xq.x;
#pragma unroll
            for (int q = 0; q < 4; ++q) {
                f[2 * q]     = __uint_as_float(p[q] << 16);
                f[2 * q + 1] = __uint_as_float(p[q] & 0xffff0000u);
            }
#pragma unroll
            for (int i = 0; i < 4; ++i)
#pragma unroll
                for (int j = 0; j < 8; ++j) bacc[i][j] = BCOEF[i][0] * f[j];
        }
#pragma unroll
        for (int k = 1; k <= 8; ++k) {
            uint4 q4 = ok ? reinterpret_cast<const uint4*>(
                                psi + ((size_t)(k - 1) * NODES + node) * FDIM)[c] : z;
            const uint* p = &q4.x;
#pragma unroll
            for (int q = 0; q < 4; ++q) {
                f[2 * q]     = __uint_as_float(p[q] << 16);
                f[2 * q + 1] = __uint_as_float(p[q] & 0xffff0000u);
            }
#pragma unroll
            for (int i = 0; i < 4; ++i)
#pragma unroll
                for (int j = 0; j < 8; ++j) bacc[i][j] += BCOEF[i][k] * f[j];
        }
#pragma unroll
        for (int i = 0; i < 4; ++i) {
            bf16x8 bv;
#pragma unroll
            for (int j = 0; j < 8; ++j) bv[j] = (__bf16)bacc[i][j];
            *reinterpret_cast<bf16x8*>(&SW[RIDX(i, row, c)]) = bv;
        }
    }

    // 9-matrix pipeline: mats 0..3 band GEMMs (H_i written at iter i+1),
    // mats 4..8 fuse GEMM over slots {H0,H1,H2,H3,X}.
    f32x4 facc[2], hacc[2];
#pragma unroll
    for (int n = 0; n < 2; ++n) facc[n] = (f32x4){0.f, 0.f, 0.f, 0.f};

    for (int mi = 0; mi < 9; ++mi) {
        // stage Wt for matrix mi: linear LDS dest, inverse-swizzled global source
        {
            const ushort* Wm = Wp + (size_t)mi * 16384;
#pragma unroll
            for (int it = 0; it < 4; ++it) {
                int ci = it * 512 + w * 64 + l;        // 0..2047
                int o = ci >> 4, cc = ci & 15;
                int csrc = cc ^ (o & 15);
                gload_lds16(Wm + o * 128 + csrc * 8,
                            (void*)(SW + (size_t)(2560 + it * 512 + w * 64) * 8));
            }
        }
        // write H_{mi-1} (band output) into its slot while DMA is in flight
        if (mi >= 1 && mi <= 4) {
            int i = mi - 1;
#pragma unroll
            for (int n = 0; n < 2; ++n) {
#pragma unroll
                for (int r = 0; r < 4; ++r) {
                    float h = hacc[n][r] + bb[i][n];
                    h = h > 0.f ? h : 0.f;
                    int row = m * 16 + hi * 4 + r;
                    int o   = (nb + n) * 16 + lo;
                    SW[((i << 9) + (row << 4) + ((o >> 3) ^ (row & 15))) * 8 + (o & 7)] = (__bf16)h;
                }
            }
        }
        __syncthreads();   // vmcnt(0)+bar: Wt ready, H/band writes visible

        int slot = (mi < 4) ? mi : (mi - 4);
        if (mi < 4) {
#pragma unroll
            for (int n = 0; n < 2; ++n) hacc[n] = (f32x4){0.f, 0.f, 0.f, 0.f};
#pragma unroll
            for (int k = 0; k < 4; ++k) {
                bf16x8 a = *reinterpret_cast<const bf16x8*>(&SW[RIDX(slot, m * 16 + lo, k * 4 + hi)]);
#pragma unroll
                for (int n = 0; n < 2; ++n) {
                    bf16x8 b = *reinterpret_cast<const bf16x8*>(&SW[WIDX((nb + n) * 16 + lo, k * 4 + hi)]);
                    hacc[n] = __builtin_amdgcn_mfma_f32_16x16x32_bf16(a, b, hacc[n], 0, 0, 0);
                }
            }
        } else {
#pragma unroll
            for (int k = 0; k < 4; ++k) {
                bf16x8 a = *reinterpret_cast<const bf16x8*>(&SW[RIDX(slot, m * 16 + lo, k * 4 + hi)]);
#pragma unroll
                for (int n = 0; n < 2; ++n) {
                    bf16x8 b = *reinterpret_cast<const bf16x8*>(&SW[WIDX((nb + n) * 16 + lo, k * 4 + hi)]);
                    facc[n] = __builtin_amdgcn_mfma_f32_16x16x32_bf16(a, b, facc[n], 0, 0, 0);
                }
            }
        }
        __syncthreads();   // Wt/slot reads done before next stage/overwrite
    }

#pragma unroll
    for (int n = 0; n < 2; ++n) {
#pragma unroll
        for (int r = 0; r < 4; ++r) {
            int node = n0 + m * 16 + hi * 4 + r;
            if (node < NODES)
                out[(size_t)node * FDIM + (nb + n) * 16 + lo] = facc[n][r] + bf[n];
        }
    }
}

extern "C" void kernel_launch(void* const* d_in, const int* in_sizes, int n_in,
                              void* d_out, int out_size, void* d_ws, size_t ws_size,
                              hipStream_t stream) {
    (void)in_sizes; (void)n_in; (void)out_size;
    const float* X      = (const float*)d_in[0];
    const int*   erow   = (const int*)d_in[1];
    const int*   ecol   = (const int*)d_in[2];
    const float* ew     = (const float*)d_in[3];
    const float* W_band = (const float*)d_in[4];
    const float* b_band = (const float*)d_in[5];
    const float* W_fuse = (const float*)d_in[6];
    const float* b_fuse = (const float*)d_in[7];
    float* out = (float*)d_out;

    // workspace layout (bf16 psi)
    ushort* psi    = (ushort*)d_ws;                         // 8*N*128 bf16
    ushort* Xb     = psi + (size_t)8 * NODES * FDIM;        // N*128 bf16
    ushort* Wp     = Xb + (size_t)NODES * FDIM;             // 9*128*128 bf16
    int*    rowptr = (int*)(Wp + 9 * 128 * 128);            // N+1
    int*    cursor = rowptr + NODES + 1;                    // N (+1 pad for int2 align)
    int2*   ev     = (int2*)(cursor + NODES + 1);           // E (col, w)
    size_t needed = ((size_t)8 * NODES * FDIM + (size_t)NODES * FDIM + 9 * 128 * 128) * 2
                  + ((size_t)2 * NODES + 2) * 4 + (size_t)NEDGE * 8;
    if (ws_size < needed) return;

    // CSR build + precision prep
    hipMemsetAsync(cursor, 0, NODES * sizeof(int), stream);
    hist_kernel<<<(NEDGE + 255) / 256, 256, 0, stream>>>(erow, cursor, NEDGE);
    scan_kernel<<<1, 1024, 0, stream>>>(cursor, rowptr, NODES);
    hipMemcpyAsync(cursor, rowptr, NODES * sizeof(int), hipMemcpyDeviceToDevice, stream);
    scatter_kernel<<<(NEDGE + 255) / 256, 256, 0, stream>>>(erow, ecol, ew, cursor, ev, NEDGE);
    prep_x<<<(NODES * FDIM / 4 + 255) / 256, 256, 0, stream>>>(X, Xb, NODES * FDIM / 4);
    prep_w<<<(9 * 128 * 128 + 255) / 256, 256, 0, stream>>>(W_band, W_fuse, Wp);

    // Chebyshev recurrence in bf16 storage / f32 accumulate
    spmm4<<<NODES / 4, 256, 0, stream>>>(rowptr, ev, Xb, nullptr, psi, 1.0f, NODES);
    for (int k = 2; k <= 8; ++k) {
        const ushort* pin  = psi + (size_t)(k - 2) * NODES * FDIM;
        const ushort* psub = (k == 2) ? Xb : psi + (size_t)(k - 3) * NODES * FDIM;
        ushort*       pout = psi + (size_t)(k - 1) * NODES * FDIM;
        spmm4<<<NODES / 4, 256, 0, stream>>>(rowptr, ev, pin, psub, pout, 2.0f, NODES);
    }

    // bands + band GEMMs + fuse GEMM (bf16 MFMA, f32 accum)
    epilogue_kernel<<<(NODES + 31) / 32, 512, 0, stream>>>(
        Xb, psi, Wp, b_band, b_fuse, out);
}